// Round 3
// baseline (846.486 us; speedup 1.0000x reference)
//
#include <hip/hip_runtime.h>
#include <hip/hip_bf16.h>

#define B_ 8
#define T_ 256
#define U_ 65
#define V_ 1024
#define DIAGS (T_ + U_ - 1)   // 320
#define DSTRIDE (DIAGS * U_)  // 20800 floats per batch per array
#define PF 8                  // consumer prefetch depth (diagonals)
#define SENT 0xFFFFFFFFu      // -NaN sentinel; real lp values are finite

// Agent-scope (device-wide, cross-XCD coherent) relaxed atomic access.
// Producer stores write through to the coherence point; consumer loads
// bypass stale local caches. The loaded VALUE doubles as the ready flag.
__device__ __forceinline__ unsigned ld_agent(const float* p) {
  return __hip_atomic_load((const unsigned*)p, __ATOMIC_RELAXED,
                           __HIP_MEMORY_SCOPE_AGENT);
}
__device__ __forceinline__ void st_agent(float* p, float v) {
  __hip_atomic_store((unsigned*)p, __float_as_uint(v), __ATOMIC_RELAXED,
                     __HIP_MEMORY_SCOPE_AGENT);
}

// fast logaddexp: max + log(1+exp(-|x-y|)); inputs finite by construction.
__device__ __forceinline__ float laddexp(float x, float y) {
  float m = fmaxf(x, y);
  return m + __logf(1.0f + __expf(-fabsf(x - y)));
}

// Fused kernel.
//  blocks 1..16640: producers. Block i, wave wv handles cell r = i-1 of
//    batch b = wv (cell-major across batches -> all batches' early diagonals
//    are produced first, so consumers trail uniformly).
//    Writes (diagonal-major layout, agent-scope stores):
//      blankD[b][(t+u)*U + u]       = lp[b,t,u,0]
//      labelD[b][(t+u+1)*U + (u+1)] = lp[b,t,u,labels[b,u]]  (u < U-1)
//  block 0: consumer. Wave wv runs the alpha recursion for batch wv over
//    anti-diagonals d = t+u; lane u holds alpha[.,u] (lane 63 also u=64).
//    Each stage's inputs are polled until non-sentinel.
__global__ __launch_bounds__(512) void rnnt_fused_kernel(
    const float* __restrict__ acts, const int* __restrict__ labels,
    const int* __restrict__ act_lens, const int* __restrict__ label_lens,
    float* __restrict__ blankD, float* __restrict__ labelD,
    float* __restrict__ out) {
  const int wv = threadIdx.x >> 6;
  const int lane = threadIdx.x & 63;

  if (blockIdx.x != 0) {
    // ---------------- producer ----------------
    const int wg = (blockIdx.x - 1) * 8 + wv;  // 0 .. 133119
    const int b = wg & 7;
    const int r = wg >> 3;         // 0 .. 16639 (cell index, t-major)
    const int t = r / U_;
    const int u = r - t * U_;

    const float* __restrict__ p =
        acts + (((size_t)b * T_ + t) * U_ + u) * V_;
    const float4* __restrict__ p4 = (const float4*)p;
    float4 v0 = p4[lane];
    float4 v1 = p4[64 + lane];
    float4 v2 = p4[128 + lane];
    float4 v3 = p4[192 + lane];

    float m = fmaxf(fmaxf(fmaxf(v0.x, v0.y), fmaxf(v0.z, v0.w)),
                    fmaxf(fmaxf(v1.x, v1.y), fmaxf(v1.z, v1.w)));
    m = fmaxf(m, fmaxf(fmaxf(fmaxf(v2.x, v2.y), fmaxf(v2.z, v2.w)),
                       fmaxf(fmaxf(v3.x, v3.y), fmaxf(v3.z, v3.w))));
    #pragma unroll
    for (int off = 32; off; off >>= 1) m = fmaxf(m, __shfl_xor(m, off, 64));

    float s = (__expf(v0.x - m) + __expf(v0.y - m)) +
              (__expf(v0.z - m) + __expf(v0.w - m));
    s += (__expf(v1.x - m) + __expf(v1.y - m)) +
         (__expf(v1.z - m) + __expf(v1.w - m));
    s += (__expf(v2.x - m) + __expf(v2.y - m)) +
         (__expf(v2.z - m) + __expf(v2.w - m));
    s += (__expf(v3.x - m) + __expf(v3.y - m)) +
         (__expf(v3.z - m) + __expf(v3.w - m));
    #pragma unroll
    for (int off = 32; off; off >>= 1) s += __shfl_xor(s, off, 64);

    float lse = m + __logf(s);

    if (lane == 0) {
      st_agent(blankD + b * DSTRIDE + (t + u) * U_ + u, v0.x - lse);
      if (u < U_ - 1) {
        const int lab = labels[b * (U_ - 1) + u];
        st_agent(labelD + b * DSTRIDE + (t + u + 1) * U_ + (u + 1),
                 p[lab] - lse);
      }
    }
    return;
  }

  // ---------------- consumer (block 0) ----------------
  const float* __restrict__ BD = blankD + wv * DSTRIDE;
  const float* __restrict__ LD = labelD + wv * DSTRIDE;

  const int t_end = act_lens[wv] - 1;   // >= 127
  const int u_end = label_lens[wv];     // 32..64
  const int d_end = t_end + u_end;      // 159..319
  const bool use64 = (u_end == 64);

  float a = 0.f;    // alpha at u = lane on the current wavefront
  float a64 = 0.f;  // lane 63: alpha at u = 64
  float cap = 0.f;  // captured alpha[t_end, u_end]

  // slot j holds bits for diag d = base+j:
  //   bdb[j]=BD[(d-1)*U+lane], ldb[j]=LD[d*U+lane], + u=64 broadcasts
  unsigned bdb[PF], ldb[PF], b64b[PF], l64b[PF];
  #pragma unroll
  for (int j = 0; j < PF; ++j) {
    const int rb = (j >= 1) ? (j - 1) : 0;
    bdb[j] = ld_agent(BD + rb * U_ + lane);
    ldb[j] = ld_agent(LD + j * U_ + lane);
    b64b[j] = ld_agent(BD + rb * U_ + 64);
    l64b[j] = ld_agent(LD + j * U_ + 64);
  }

  for (int d = 0; d <= d_end; d += PF) {
    #pragma unroll
    for (int j = 0; j < PF; ++j) {
      const int dd = d + j;
      if (dd > d_end) break;  // wave-uniform

      const int t = dd - lane;
      const int t64 = dd - 64;
      // need-predicates == exact use conditions; every needed value is
      // eventually written by a valid producer cell (proof in layout map)
      const bool need_bd = (t >= 1) && (t < T_);
      const bool need_ld = (lane >= 1) && (t >= 0) && (t < T_);
      const bool is63 = (lane == 63);
      const bool need_b64 = is63 && (t64 >= 1) && (t64 < T_);
      const bool need_l64 = is63 && (t64 >= 0) && (t64 < T_);

      int guard = 0;
      while (true) {
        const bool ok = (!need_bd || bdb[j] != SENT) &&
                        (!need_ld || ldb[j] != SENT) &&
                        (!need_b64 || b64b[j] != SENT) &&
                        (!need_l64 || l64b[j] != SENT);
        if (__ballot(ok) == ~0ull) break;
        if (++guard > 65536) break;  // bailout: fail loud, don't hang
        const int rb = (dd >= 1) ? (dd - 1) : 0;
        bdb[j] = ld_agent(BD + rb * U_ + lane);
        ldb[j] = ld_agent(LD + dd * U_ + lane);
        b64b[j] = ld_agent(BD + rb * U_ + 64);
        l64b[j] = ld_agent(LD + dd * U_ + 64);
      }

      const float am1 = __shfl_up(a, 1, 64);  // alpha[prev diag][lane-1]
      const float pa = a;
      const float pa64 = a64;
      const float bd = __uint_as_float(bdb[j]);
      const float ld = __uint_as_float(ldb[j]);

      if (t >= 0 && t < T_) {
        float na;
        if (t == 0) {
          na = (lane == 0) ? 0.f : (am1 + ld);  // label-only edge
        } else if (lane == 0) {
          na = pa + bd;                          // blank-only edge
        } else {
          na = laddexp(pa + bd, am1 + ld);
        }
        a = na;
      }
      if (is63 && t64 >= 0 && t64 < T_) {  // u = 64 cell
        a64 = (t64 == 0)
                  ? (pa + __uint_as_float(l64b[j]))
                  : laddexp(pa64 + __uint_as_float(b64b[j]),
                            pa + __uint_as_float(l64b[j]));
      }
      if (dd == d_end) cap = use64 ? a64 : a;

      // refill slot j for diag dd+PF (only if that stage will run)
      const int nd = dd + PF;
      if (nd <= d_end) {
        bdb[j] = ld_agent(BD + (nd - 1) * U_ + lane);
        ldb[j] = ld_agent(LD + nd * U_ + lane);
        b64b[j] = ld_agent(BD + (nd - 1) * U_ + 64);
        l64b[j] = ld_agent(LD + nd * U_ + 64);
      }
    }
  }

  const int src = use64 ? 63 : u_end;
  const float alpha_end = __shfl(cap, src, 64);

  __shared__ float partial[B_];
  if (lane == 0) {
    unsigned fb;
    int guard = 0;
    do {  // lp_blank[t_end, u_end] lives at BD[d_end*U + u_end]
      fb = ld_agent(BD + d_end * U_ + u_end);
    } while (fb == SENT && ++guard < 1000000);
    partial[wv] = -(alpha_end + __uint_as_float(fb)) * (1.0f / B_);
  }
  __syncthreads();
  if (threadIdx.x == 0) {
    float s = 0.f;
    #pragma unroll
    for (int i = 0; i < B_; ++i) s += partial[i];
    out[0] = s;
  }
}

extern "C" void kernel_launch(void* const* d_in, const int* in_sizes, int n_in,
                              void* d_out, int out_size, void* d_ws, size_t ws_size,
                              hipStream_t stream) {
  const float* acts = (const float*)d_in[0];
  const int* labels = (const int*)d_in[1];
  const int* act_lens = (const int*)d_in[2];
  const int* label_lens = (const int*)d_in[3];
  float* out = (float*)d_out;

  float* blankD = (float*)d_ws;                 // B*DSTRIDE floats
  float* labelD = blankD + (size_t)B_ * DSTRIDE;

  // Sentinel-init the lattice arrays (never trust harness poison value).
  hipMemsetAsync(d_ws, 0xFF, (size_t)2 * B_ * DSTRIDE * sizeof(float), stream);

  // 1 consumer block + 16640 producer blocks (8 rows each = 133120 rows)
  rnnt_fused_kernel<<<1 + (B_ * T_ * U_) / 8, 512, 0, stream>>>(
      acts, labels, act_lens, label_lens, blankD, labelD, out);
}